// Round 2
// baseline (2006.340 us; speedup 1.0000x reference)
//
#include <hip/hip_runtime.h>
#include <hip/hip_bf16.h>
#include <math.h>

constexpr int B_ = 16, C_ = 96, O_ = 48, R_ = 4, H_ = 66, W_ = 66;
constexpr int HW_ = H_ * W_;            // 4356
constexpr int HO_ = 64, WO_ = 64;       // valid-conv output spatial
constexpr float EPS_ = 2e-5f;

// workspace layout (float offsets)
constexpr int WS_SUM   = 0;
constexpr int WS_SUMSQ = WS_SUM + C_;
constexpr int WS_SCALE = WS_SUMSQ + C_;
constexpr int WS_SHIFT = WS_SCALE + C_;
constexpr int WS_SAVG  = WS_SHIFT + C_;                    // [B][C][R]
constexpr int WS_SMAX  = WS_SAVG + B_*C_*R_;
constexpr int WS_CHATT = WS_SMAX + B_*C_*R_;               // [B][h][C][r]
constexpr int WS_UMEAN = WS_CHATT + B_*R_*C_*R_;           // [B][r][HW]
constexpr int WS_UMAX  = WS_UMEAN + B_*R_*HW_;
constexpr int WS_SPATT = WS_UMAX + B_*R_*HW_;              // [B][h][HW]
// end = WS_SPATT + B*R*HW = 873600 floats = 3.5 MB

__device__ __forceinline__ float sigm(float v){ return 1.0f/(1.0f + __expf(-v)); }

// ---- K1: BN batch statistics (sum, sumsq per channel) ----
__global__ void k_bn_stats(const float* __restrict__ x, float* __restrict__ ws) {
  int b = blockIdx.x, c = blockIdx.y;
  const float4* p = (const float4*)(x + (size_t)(b*C_ + c) * (R_*HW_));
  int tid = threadIdx.x;
  float s = 0.f, ss = 0.f;
  for (int i = tid; i < R_*HW_/4; i += 256) {   // 17424/4 = 4356
    float4 v = p[i];
    s += v.x + v.y + v.z + v.w;
    ss += v.x*v.x + v.y*v.y + v.z*v.z + v.w*v.w;
  }
  __shared__ float rs[256], rq[256];
  rs[tid] = s; rq[tid] = ss; __syncthreads();
  for (int off = 128; off > 0; off >>= 1) {
    if (tid < off) { rs[tid] += rs[tid+off]; rq[tid] += rq[tid+off]; }
    __syncthreads();
  }
  if (tid == 0) {
    atomicAdd(&ws[WS_SUM + c], rs[0]);
    atomicAdd(&ws[WS_SUMSQ + c], rq[0]);
  }
}

// ---- K2: finalize scale/shift ----
__global__ void k_bn_finalize(const float* __restrict__ gamma, const float* __restrict__ beta,
                              float* __restrict__ ws) {
  int c = threadIdx.x;
  if (c < C_) {
    float n = (float)(B_ * R_ * HW_);
    float mu = ws[WS_SUM + c] / n;
    float var = ws[WS_SUMSQ + c] / n - mu*mu;
    float sc = gamma[c] * rsqrtf(var + EPS_);
    ws[WS_SCALE + c] = sc;
    ws[WS_SHIFT + c] = beta[c] - mu * sc;
  }
}

// ---- K3: per-(b,c,r) spatial mean/max of y = relu(bn(x)) ----
__global__ void k_sstats(const float* __restrict__ x, float* __restrict__ ws) {
  int r = blockIdx.x, c = blockIdx.y, b = blockIdx.z;
  int tid = threadIdx.x;
  float sc = ws[WS_SCALE + c], sh = ws[WS_SHIFT + c];
  const float4* p = (const float4*)(x + (size_t)((b*C_ + c)*R_ + r) * HW_);
  float s = 0.f, m = 0.f;
  for (int i = tid; i < HW_/4; i += 256) {   // 4356/4 = 1089
    float4 v = p[i];
    float a0 = fmaxf(fmaf(v.x, sc, sh), 0.f);
    float a1 = fmaxf(fmaf(v.y, sc, sh), 0.f);
    float a2 = fmaxf(fmaf(v.z, sc, sh), 0.f);
    float a3 = fmaxf(fmaf(v.w, sc, sh), 0.f);
    s += a0+a1+a2+a3; m = fmaxf(fmaxf(fmaxf(m, a0), fmaxf(a1, a2)), a3);
  }
  __shared__ float rs[256], rm[256];
  rs[tid] = s; rm[tid] = m; __syncthreads();
  for (int off = 128; off > 0; off >>= 1) {
    if (tid < off) { rs[tid] += rs[tid+off]; rm[tid] = fmaxf(rm[tid], rm[tid+off]); }
    __syncthreads();
  }
  if (tid == 0) {
    int idx = (b*C_ + c)*R_ + r;
    ws[WS_SAVG + idx] = rs[0] / (float)HW_;
    ws[WS_SMAX + idx] = rm[0];
  }
}

// ---- K4: channel-pooled maps u_mean/u_max over C at each (b,r,pos) ----
__global__ void k_upool(const float* __restrict__ x, float* __restrict__ ws) {
  int r = blockIdx.y, b = blockIdx.z;
  int pos = blockIdx.x*256 + threadIdx.x;
  if (pos >= HW_) return;
  float s = 0.f, m = 0.f;
  for (int c = 0; c < C_; ++c) {
    float v = fmaxf(fmaf(x[(size_t)((b*C_ + c)*R_ + r)*HW_ + pos],
                         ws[WS_SCALE+c], ws[WS_SHIFT+c]), 0.f);
    s += v; m = fmaxf(m, v);
  }
  int idx = (b*R_ + r)*HW_ + pos;
  ws[WS_UMEAN + idx] = s / (float)C_;
  ws[WS_UMAX + idx] = m;
}

// ---- K5: channel attention MLP (E=2, tiny) ----
__global__ void k_chatt(const float* __restrict__ fc1, const float* __restrict__ fc2,
                        float* __restrict__ ws) {
  int b = blockIdx.x, tid = threadIdx.x;
  __shared__ float sA[C_*R_], sM[C_*R_], hs[8];
  for (int i = tid; i < C_*R_; i += 256) {
    sA[i] = ws[WS_SAVG + b*C_*R_ + i];
    sM[i] = ws[WS_SMAX + b*C_*R_ + i];
  }
  __syncthreads();
  if (tid < 8) {
    int h = tid >> 1, e = tid & 1;
    float aA = 0.f, aM = 0.f;
    for (int c = 0; c < C_; ++c)
      for (int r = 0; r < R_; ++r) {
        float w = fc1[(e*C_ + c)*R_ + ((r - h) & 3)];   // roll(fc1,h,axis=2)
        aA += sA[c*R_ + r] * w;
        aM += sM[c*R_ + r] * w;
      }
    hs[tid] = fmaxf(aA, 0.f) + fmaxf(aM, 0.f);   // relu per path, then sum (shared fc2)
  }
  __syncthreads();
  for (int idx = tid; idx < R_*C_*R_; idx += 256) {
    int h = idx / (C_*R_);
    int c = (idx % (C_*R_)) / R_;
    int r = idx & 3;
    int rr = (r - h) & 3;
    float v = hs[h*2+0] * fc2[(c*2+0)*R_ + rr]
            + hs[h*2+1] * fc2[(c*2+1)*R_ + rr];
    ws[WS_CHATT + b*R_*C_*R_ + idx] = sigm(v);
  }
}

// ---- K6: spatial attention 7x7 group conv (rot90 source map) ----
__global__ void k_spatt(const float* __restrict__ saw, float* __restrict__ ws) {
  int h = blockIdx.y, b = blockIdx.z;
  int tid = threadIdx.x;
  __shared__ float wl[2*R_*49];
  for (int e = tid; e < 2*R_*49; e += 256) {
    int g = e / (R_*49);
    int s = (e / 49) % R_;
    int ij = e % 49;
    int i = ij / 7, j = ij % 7;
    int si, sj;
    if (h == 0)      { si = i;     sj = j;     }
    else if (h == 1) { si = j;     sj = 6 - i; }
    else if (h == 2) { si = 6 - i; sj = 6 - j; }
    else             { si = 6 - j; sj = i;     }
    int srot = (s - h) & 3;
    wl[e] = saw[(g*R_ + srot)*49 + si*7 + sj];
  }
  __syncthreads();
  int pos = blockIdx.x*256 + tid;
  if (pos >= HW_) return;
  int y = pos / W_, xx = pos % W_;
  float acc = 0.f;
  for (int g = 0; g < 2; ++g) {
    const float* u = ws + (g ? WS_UMAX : WS_UMEAN) + (size_t)b*R_*HW_;
    for (int s = 0; s < R_; ++s) {
      const float* up = u + s*HW_;
      const float* wp = wl + (g*R_ + s)*49;
      for (int i = 0; i < 7; ++i) {
        int yy = y + i - 3;
        if (yy < 0 || yy >= H_) continue;
        for (int j = 0; j < 7; ++j) {
          int xc = xx + j - 3;
          if (xc < 0 || xc >= W_) continue;
          acc += up[yy*W_ + xc] * wp[i*7 + j];
        }
      }
    }
  }
  ws[WS_SPATT + (b*R_ + h)*HW_ + pos] = sigm(acc);
}

// ---- K7: main attention-gated group conv (direct, fp32-VALU roofline shaped) ----
// block = 192 threads (3 waves): o = t%48, xb = (t/48)*16.
// Each thread: acc[4][16] (4 output rows x 16 cols for one o).
__global__ __launch_bounds__(192) void k_conv(
    const float* __restrict__ x, const float* __restrict__ cw,
    const float* __restrict__ ws, float* __restrict__ out) {
  int ytile = blockIdx.x, h = blockIdx.y, b = blockIdx.z;
  int y0 = ytile * 4;
  int t = threadIdx.x;
  int o = t % O_;
  int xb = (t / O_) * 16;

  __shared__ float satt[6*W_];   // sp_att rows y0..y0+5
  __shared__ float zl[6*68];     // gated input tile (stride 68: float4-aligned)
  __shared__ float wl[O_*9];     // rotated weights for current (c,r)

  const float* sp = ws + WS_SPATT + (size_t)(b*R_ + h)*HW_;
  for (int e = t; e < 6*W_; e += 192)
    satt[e] = sp[(y0 + e/W_)*W_ + e%W_];

  float acc[4][16];
  #pragma unroll
  for (int dy = 0; dy < 4; ++dy)
    #pragma unroll
    for (int q = 0; q < 16; ++q) acc[dy][q] = 0.f;

  const float* chatt = ws + WS_CHATT + (size_t)(b*R_ + h)*C_*R_;

  for (int c = 0; c < C_; ++c) {
    float sc = ws[WS_SCALE + c], sh = ws[WS_SHIFT + c];
    for (int r = 0; r < R_; ++r) {
      __syncthreads();   // previous plane's compute done before re-staging
      const float* xp = x + (size_t)((b*C_ + c)*R_ + r)*HW_;
      float catt = chatt[c*R_ + r];
      for (int e = t; e < 6*W_; e += 192) {
        int row = e / W_, col = e % W_;
        float v = fmaxf(fmaf(xp[(y0+row)*W_ + col], sc, sh), 0.f);
        zl[row*68 + col] = v * catt * satt[e];
      }
      int rr = (r - h) & 3;
      for (int e = t; e < O_*9; e += 192) {
        int oo = e / 9, ij = e % 9;
        int i = ij / 3, j = ij % 3;
        int si, sj;
        if (h == 0)      { si = i;     sj = j;     }
        else if (h == 1) { si = j;     sj = 2 - i; }
        else if (h == 2) { si = 2 - i; sj = 2 - j; }
        else             { si = 2 - j; sj = i;     }
        wl[e] = cw[((size_t)(oo*C_ + c)*R_ + rr)*9 + si*3 + sj];
      }
      __syncthreads();
      float wr[9];
      #pragma unroll
      for (int q = 0; q < 9; ++q) wr[q] = wl[o*9 + q];
      #pragma unroll
      for (int k = 0; k < 6; ++k) {
        float rv[18];
        const float* zp = &zl[k*68 + xb];     // float4-aligned (68%4==0, xb%16==0)
        *(float4*)&rv[0]  = *(const float4*)&zp[0];
        *(float4*)&rv[4]  = *(const float4*)&zp[4];
        *(float4*)&rv[8]  = *(const float4*)&zp[8];
        *(float4*)&rv[12] = *(const float4*)&zp[12];
        *(float2*)&rv[16] = *(const float2*)&zp[16];
        #pragma unroll
        for (int dy = 0; dy < 4; ++dy) {
          int i = k - dy;            // input row k serves output row dy with i = k-dy
          if (i >= 0 && i < 3) {
            #pragma unroll
            for (int j = 0; j < 3; ++j) {
              float w = wr[i*3 + j];
              #pragma unroll
              for (int q = 0; q < 16; ++q)
                acc[dy][q] = fmaf(w, rv[q + j], acc[dy][q]);
            }
          }
        }
      }
    }
  }
  float* op = out + ((size_t)(b*(O_+C_) + o)*R_ + h)*((size_t)HO_*WO_);
  #pragma unroll
  for (int dy = 0; dy < 4; ++dy)
    #pragma unroll
    for (int q = 0; q < 16; ++q)
      op[(y0+dy)*WO_ + xb + q] = acc[dy][q];
}

// ---- K8: dense concat — cropped x into channels 48..143 (float4 stores) ----
__global__ void k_copy(const float* __restrict__ x, float* __restrict__ out) {
  size_t idx = (size_t)blockIdx.x * 256 + threadIdx.x;   // one float4 of output
  constexpr size_t total4 = (size_t)B_ * C_ * R_ * HO_ * WO_ / 4;
  if (idx >= total4) return;
  int x4 = idx % (WO_/4);
  int yy = (idx / (WO_/4)) % HO_;
  int r  = (idx / ((size_t)HO_*WO_/4)) % R_;
  int c  = (idx / ((size_t)HO_*WO_/4*R_)) % C_;
  int b  = (int)(idx / ((size_t)HO_*WO_/4*R_*C_));
  const float* src = x + ((size_t)(b*C_ + c)*R_ + r)*HW_ + (yy+1)*W_ + (x4*4+1);
  float4 v = make_float4(src[0], src[1], src[2], src[3]);
  *(float4*)(out + ((size_t)(b*(O_+C_) + O_ + c)*R_ + r)*((size_t)HO_*WO_)
             + yy*WO_ + x4*4) = v;
}

extern "C" void kernel_launch(void* const* d_in, const int* in_sizes, int n_in,
                              void* d_out, int out_size, void* d_ws, size_t ws_size,
                              hipStream_t stream) {
  const float* x     = (const float*)d_in[0];
  const float* gamma = (const float*)d_in[1];
  const float* beta  = (const float*)d_in[2];
  const float* fc1   = (const float*)d_in[3];
  const float* fc2   = (const float*)d_in[4];
  const float* saw   = (const float*)d_in[5];
  const float* cw    = (const float*)d_in[6];
  float* out = (float*)d_out;
  float* ws = (float*)d_ws;

  hipMemsetAsync(d_ws, 0, WS_SCALE * sizeof(float), stream);  // zero sum+sumsq
  k_bn_stats  <<<dim3(B_, C_),                256, 0, stream>>>(x, ws);
  k_bn_finalize<<<1, 128,                          0, stream>>>(gamma, beta, ws);
  k_sstats    <<<dim3(R_, C_, B_),            256, 0, stream>>>(x, ws);
  k_upool     <<<dim3((HW_+255)/256, R_, B_), 256, 0, stream>>>(x, ws);
  k_chatt     <<<B_, 256,                          0, stream>>>(fc1, fc2, ws);
  k_spatt     <<<dim3((HW_+255)/256, R_, B_), 256, 0, stream>>>(saw, ws);
  k_conv      <<<dim3(16, R_, B_),            192, 0, stream>>>(x, cw, ws, out);
  k_copy      <<<(int)(((size_t)B_*C_*R_*HO_*WO_/4 + 255)/256), 256, 0, stream>>>(x, out);
}

// Round 3
// 598.517 us; speedup vs baseline: 3.3522x; 3.3522x over previous
//
#include <hip/hip_runtime.h>
#include <hip/hip_bf16.h>
#include <math.h>

constexpr int B_ = 16, C_ = 96, O_ = 48, R_ = 4, H_ = 66, W_ = 66;
constexpr int HW_ = H_ * W_;            // 4356
constexpr int HO_ = 64, WO_ = 64;       // valid-conv output spatial
constexpr int OC_ = O_ + C_;            // 144 output channels
constexpr float EPS_ = 2e-5f;
constexpr int KP_ = 32;                 // planes per K-chunk
constexpr int NCH_ = (C_*R_)/KP_;       // 12 chunks
constexpr int PS_ = 36;                 // padded plane stride in LDS (bank de-alias)

// workspace layout (float offsets)
constexpr int WS_SUM   = 0;
constexpr int WS_SUMSQ = WS_SUM + C_;
constexpr int WS_SCALE = WS_SUMSQ + C_;
constexpr int WS_SHIFT = WS_SCALE + C_;
constexpr int WS_SAVG  = WS_SHIFT + C_;                    // [B][C][R]
constexpr int WS_SMAX  = WS_SAVG + B_*C_*R_;
constexpr int WS_CHATT = WS_SMAX + B_*C_*R_;               // [B][h][C][r]
constexpr int WS_UMEAN = WS_CHATT + B_*R_*C_*R_;           // [B][r][HW]
constexpr int WS_UMAX  = WS_UMEAN + B_*R_*HW_;
constexpr int WS_SPATT = WS_UMAX + B_*R_*HW_;              // [B][h][HW]
constexpr int WS_WROT  = WS_SPATT + B_*R_*HW_;             // bf16 [h][chunk][o][tap][PS_]
// wrot shorts = 4*12*48*9*36 = 746496 -> 373248 floats; total ws ~ 4.8 MB

typedef __attribute__((ext_vector_type(8))) __bf16 bf16x8;
typedef __attribute__((ext_vector_type(4))) float f32x4;

__device__ __forceinline__ float sigm(float v){ return 1.0f/(1.0f + __expf(-v)); }

// ---- K1: BN batch statistics ----
__global__ void k_bn_stats(const float* __restrict__ x, float* __restrict__ ws) {
  int b = blockIdx.x, c = blockIdx.y;
  const float4* p = (const float4*)(x + (size_t)(b*C_ + c) * (R_*HW_));
  int tid = threadIdx.x;
  float s = 0.f, ss = 0.f;
  for (int i = tid; i < R_*HW_/4; i += 256) {
    float4 v = p[i];
    s += v.x + v.y + v.z + v.w;
    ss += v.x*v.x + v.y*v.y + v.z*v.z + v.w*v.w;
  }
  __shared__ float rs[256], rq[256];
  rs[tid] = s; rq[tid] = ss; __syncthreads();
  for (int off = 128; off > 0; off >>= 1) {
    if (tid < off) { rs[tid] += rs[tid+off]; rq[tid] += rq[tid+off]; }
    __syncthreads();
  }
  if (tid == 0) {
    atomicAdd(&ws[WS_SUM + c], rs[0]);
    atomicAdd(&ws[WS_SUMSQ + c], rq[0]);
  }
}

// ---- K2: finalize scale/shift ----
__global__ void k_bn_finalize(const float* __restrict__ gamma, const float* __restrict__ beta,
                              float* __restrict__ ws) {
  int c = threadIdx.x;
  if (c < C_) {
    float n = (float)(B_ * R_ * HW_);
    float mu = ws[WS_SUM + c] / n;
    float var = ws[WS_SUMSQ + c] / n - mu*mu;
    float sc = gamma[c] * rsqrtf(var + EPS_);
    ws[WS_SCALE + c] = sc;
    ws[WS_SHIFT + c] = beta[c] - mu * sc;
  }
}

// ---- K3: per-(b,c,r) spatial mean/max of y + fused crop-copy to out ----
__global__ void k_sstats(const float* __restrict__ x, float* __restrict__ ws,
                         float* __restrict__ out) {
  int r = blockIdx.x, c = blockIdx.y, b = blockIdx.z;
  int tid = threadIdx.x;
  float sc = ws[WS_SCALE + c], sh = ws[WS_SHIFT + c];
  const float* xp = x + (size_t)((b*C_ + c)*R_ + r) * HW_;
  const float4* p = (const float4*)xp;
  float s = 0.f, m = 0.f;
  for (int i = tid; i < HW_/4; i += 256) {
    float4 v = p[i];
    float a0 = fmaxf(fmaf(v.x, sc, sh), 0.f);
    float a1 = fmaxf(fmaf(v.y, sc, sh), 0.f);
    float a2 = fmaxf(fmaf(v.z, sc, sh), 0.f);
    float a3 = fmaxf(fmaf(v.w, sc, sh), 0.f);
    s += a0+a1+a2+a3; m = fmaxf(fmaxf(fmaxf(m, a0), fmaxf(a1, a2)), a3);
  }
  // crop-copy x[...,1:65,1:65] -> out channels O_..O_+C_
  float* op = out + ((size_t)(b*OC_ + O_ + c)*R_ + r)*((size_t)HO_*WO_);
  for (int e = tid; e < HO_*WO_/4; e += 256) {   // 1024
    int row = e >> 4, c4 = e & 15;
    const float* sp2 = xp + (row+1)*W_ + c4*4 + 1;
    float4 v = make_float4(sp2[0], sp2[1], sp2[2], sp2[3]);
    *(float4*)(op + row*WO_ + c4*4) = v;
  }
  __shared__ float rs[256], rm[256];
  rs[tid] = s; rm[tid] = m; __syncthreads();
  for (int off = 128; off > 0; off >>= 1) {
    if (tid < off) { rs[tid] += rs[tid+off]; rm[tid] = fmaxf(rm[tid], rm[tid+off]); }
    __syncthreads();
  }
  if (tid == 0) {
    int idx = (b*C_ + c)*R_ + r;
    ws[WS_SAVG + idx] = rs[0] / (float)HW_;
    ws[WS_SMAX + idx] = rm[0];
  }
}

// ---- K4: channel-pooled maps u_mean/u_max ----
__global__ void k_upool(const float* __restrict__ x, float* __restrict__ ws) {
  int r = blockIdx.y, b = blockIdx.z;
  int pos = blockIdx.x*256 + threadIdx.x;
  if (pos >= HW_) return;
  float s = 0.f, m = 0.f;
  for (int c = 0; c < C_; ++c) {
    float v = fmaxf(fmaf(x[(size_t)((b*C_ + c)*R_ + r)*HW_ + pos],
                         ws[WS_SCALE+c], ws[WS_SHIFT+c]), 0.f);
    s += v; m = fmaxf(m, v);
  }
  int idx = (b*R_ + r)*HW_ + pos;
  ws[WS_UMEAN + idx] = s / (float)C_;
  ws[WS_UMAX + idx] = m;
}

// ---- K5: channel attention MLP ----
__global__ void k_chatt(const float* __restrict__ fc1, const float* __restrict__ fc2,
                        float* __restrict__ ws) {
  int b = blockIdx.x, tid = threadIdx.x;
  __shared__ float sA[C_*R_], sM[C_*R_], hs[8];
  for (int i = tid; i < C_*R_; i += 256) {
    sA[i] = ws[WS_SAVG + b*C_*R_ + i];
    sM[i] = ws[WS_SMAX + b*C_*R_ + i];
  }
  __syncthreads();
  if (tid < 8) {
    int h = tid >> 1, e = tid & 1;
    float aA = 0.f, aM = 0.f;
    for (int c = 0; c < C_; ++c)
      for (int r = 0; r < R_; ++r) {
        float w = fc1[(e*C_ + c)*R_ + ((r - h) & 3)];
        aA += sA[c*R_ + r] * w;
        aM += sM[c*R_ + r] * w;
      }
    hs[tid] = fmaxf(aA, 0.f) + fmaxf(aM, 0.f);
  }
  __syncthreads();
  for (int idx = tid; idx < R_*C_*R_; idx += 256) {
    int h = idx / (C_*R_);
    int c = (idx % (C_*R_)) / R_;
    int r = idx & 3;
    int rr = (r - h) & 3;
    float v = hs[h*2+0] * fc2[(c*2+0)*R_ + rr]
            + hs[h*2+1] * fc2[(c*2+1)*R_ + rr];
    ws[WS_CHATT + b*R_*C_*R_ + idx] = sigm(v);
  }
}

// ---- K6: spatial attention 7x7 group conv ----
__global__ void k_spatt(const float* __restrict__ saw, float* __restrict__ ws) {
  int h = blockIdx.y, b = blockIdx.z;
  int tid = threadIdx.x;
  __shared__ float wl[2*R_*49];
  for (int e = tid; e < 2*R_*49; e += 256) {
    int g = e / (R_*49);
    int s = (e / 49) % R_;
    int ij = e % 49;
    int i = ij / 7, j = ij % 7;
    int si, sj;
    if (h == 0)      { si = i;     sj = j;     }
    else if (h == 1) { si = j;     sj = 6 - i; }
    else if (h == 2) { si = 6 - i; sj = 6 - j; }
    else             { si = 6 - j; sj = i;     }
    int srot = (s - h) & 3;
    wl[e] = saw[(g*R_ + srot)*49 + si*7 + sj];
  }
  __syncthreads();
  int pos = blockIdx.x*256 + tid;
  if (pos >= HW_) return;
  int y = pos / W_, xx = pos % W_;
  float acc = 0.f;
  for (int g = 0; g < 2; ++g) {
    const float* u = ws + (g ? WS_UMAX : WS_UMEAN) + (size_t)b*R_*HW_;
    for (int s = 0; s < R_; ++s) {
      const float* up = u + s*HW_;
      const float* wp = wl + (g*R_ + s)*49;
      for (int i = 0; i < 7; ++i) {
        int yy = y + i - 3;
        if (yy < 0 || yy >= H_) continue;
        for (int j = 0; j < 7; ++j) {
          int xc = xx + j - 3;
          if (xc < 0 || xc >= W_) continue;
          acc += up[yy*W_ + xc] * wp[i*7 + j];
        }
      }
    }
  }
  ws[WS_SPATT + (b*R_ + h)*HW_ + pos] = sigm(acc);
}

// ---- K7: pre-rotate + pack conv weights to bf16 in the LDS image layout ----
// wrot[h][chunk][o][tap][PS_] (bf16), tap = i*3+j, plane pl within chunk
__global__ void k_wrot(const float* __restrict__ cw, float* __restrict__ ws) {
  int chunk = blockIdx.x, h = blockIdx.y;
  __bf16* wp = (__bf16*)(ws + WS_WROT) + (size_t)(h*NCH_ + chunk)*(O_*9*PS_);
  for (int e = threadIdx.x; e < O_*9*KP_; e += 256) {
    int o = e / (9*KP_);
    int s = e % (9*KP_);
    int tap = s / KP_, pl = s % KP_;
    int p = chunk*KP_ + pl;
    int c = p >> 2, r = p & 3;
    int rr = (r - h) & 3;
    int i = tap / 3, j = tap % 3;
    int si, sj;
    if (h == 0)      { si = i;     sj = j;     }
    else if (h == 1) { si = j;     sj = 2 - i; }
    else if (h == 2) { si = 2 - i; sj = 2 - j; }
    else             { si = 2 - j; sj = i;     }
    wp[(o*9 + tap)*PS_ + pl] = (__bf16)cw[((size_t)(o*C_ + c)*R_ + rr)*9 + si*3 + sj];
  }
}

// ---- K8: main conv via MFMA implicit GEMM ----
// block 512 (8 waves). Out tile: 4 rows x 64 cols x 48 O for one (b,h).
// wave w: dy = w>>1, g in {(w&1)*2, (w&1)*2+1}; acc[nt(3)][gi(2)] 16x16 tiles.
// A = weights [m=o][k=plane], B = z [k=plane][n=spatial col].
__global__ __launch_bounds__(512) void k_conv(
    const float* __restrict__ x, const float* __restrict__ ws,
    float* __restrict__ out) {
  int ytile = blockIdx.x, h = blockIdx.y, b = blockIdx.z;
  int y0 = ytile * 4;
  int tid = threadIdx.x;
  int lane = tid & 63, wave = tid >> 6;
  int m = lane & 15, quad = lane >> 4;
  int dy = wave >> 1, gp = (wave & 1) * 2;

  __shared__ __align__(16) __bf16 zl[6*W_*PS_];      // 14256*... (row*66+col)*36+pl
  __shared__ __align__(16) __bf16 wl[O_*9*PS_];      // (o*9+tap)*36+pl
  __shared__ float satt_l[6*W_];
  __shared__ float catt_l[C_*R_];
  __shared__ float scl[C_], shl[C_];

  const float* sp = ws + WS_SPATT + (size_t)(b*R_ + h)*HW_;
  for (int e = tid; e < 6*W_; e += 512) satt_l[e] = sp[(y0 + e/W_)*W_ + e%W_];
  const float* chatt = ws + WS_CHATT + (size_t)(b*R_ + h)*C_*R_;
  for (int e = tid; e < C_*R_; e += 512) catt_l[e] = chatt[e];
  for (int e = tid; e < C_; e += 512) { scl[e] = ws[WS_SCALE+e]; shl[e] = ws[WS_SHIFT+e]; }

  f32x4 acc[3][2];
  #pragma unroll
  for (int nt = 0; nt < 3; ++nt)
    #pragma unroll
    for (int gi = 0; gi < 2; ++gi) acc[nt][gi] = (f32x4){0.f,0.f,0.f,0.f};

  const __bf16* wrot = (const __bf16*)(ws + WS_WROT);

  for (int chunk = 0; chunk < NCH_; ++chunk) {
    __syncthreads();   // previous chunk's reads done
    // stage z: 32 planes x 6 rows x 33 col-pairs
    for (int e = tid; e < KP_*6*33; e += 512) {
      int pl = e / 198;
      int s = e - pl*198;
      int row = s / 33;
      int cp = s - row*33;
      int p = chunk*KP_ + pl;
      int c = p >> 2, r = p & 3;
      const float* xp = x + (size_t)((b*C_ + c)*R_ + r)*HW_ + (y0+row)*W_ + cp*2;
      float2 xv = *(const float2*)xp;
      float sc = scl[c], sh = shl[c];
      float ca = catt_l[p];
      float v0 = fmaxf(fmaf(xv.x, sc, sh), 0.f) * ca * satt_l[row*W_ + cp*2];
      float v1 = fmaxf(fmaf(xv.y, sc, sh), 0.f) * ca * satt_l[row*W_ + cp*2 + 1];
      int zi = (row*W_ + cp*2)*PS_ + pl;
      zl[zi] = (__bf16)v0;
      zl[zi + PS_] = (__bf16)v1;
    }
    // stage weights: straight uint4 copy of the precomputed padded image
    {
      const uint4* wsrc = (const uint4*)(wrot + (size_t)(h*NCH_ + chunk)*(O_*9*PS_));
      uint4* wdst = (uint4*)wl;
      for (int e = tid; e < O_*9*PS_/8; e += 512) wdst[e] = wsrc[e];   // 1944
    }
    __syncthreads();
    #pragma unroll
    for (int i = 0; i < 3; ++i) {
      #pragma unroll
      for (int j = 0; j < 3; ++j) {
        int tap = i*3 + j;
        bf16x8 zf[2], wf[3];
        #pragma unroll
        for (int gi = 0; gi < 2; ++gi) {
          int col = (gp + gi)*16 + m + j;
          zf[gi] = *(const bf16x8*)&zl[((dy + i)*W_ + col)*PS_ + quad*8];
        }
        #pragma unroll
        for (int nt = 0; nt < 3; ++nt)
          wf[nt] = *(const bf16x8*)&wl[((nt*16 + m)*9 + tap)*PS_ + quad*8];
        #pragma unroll
        for (int nt = 0; nt < 3; ++nt)
          #pragma unroll
          for (int gi = 0; gi < 2; ++gi)
            acc[nt][gi] = __builtin_amdgcn_mfma_f32_16x16x32_bf16(
                wf[nt], zf[gi], acc[nt][gi], 0, 0, 0);
      }
    }
  }
  // epilogue: D layout col(n=spatial)=lane&15, row(m=o_local)=quad*4+e
  #pragma unroll
  for (int nt = 0; nt < 3; ++nt)
    #pragma unroll
    for (int gi = 0; gi < 2; ++gi) {
      int col = (gp + gi)*16 + m;
      #pragma unroll
      for (int e = 0; e < 4; ++e) {
        int o = nt*16 + quad*4 + e;
        out[((size_t)(b*OC_ + o)*R_ + h)*((size_t)HO_*WO_) + (y0+dy)*WO_ + col] =
            acc[nt][gi][e];
      }
    }
}

extern "C" void kernel_launch(void* const* d_in, const int* in_sizes, int n_in,
                              void* d_out, int out_size, void* d_ws, size_t ws_size,
                              hipStream_t stream) {
  const float* x     = (const float*)d_in[0];
  const float* gamma = (const float*)d_in[1];
  const float* beta  = (const float*)d_in[2];
  const float* fc1   = (const float*)d_in[3];
  const float* fc2   = (const float*)d_in[4];
  const float* saw   = (const float*)d_in[5];
  const float* cw    = (const float*)d_in[6];
  float* out = (float*)d_out;
  float* ws = (float*)d_ws;

  hipMemsetAsync(d_ws, 0, WS_SCALE * sizeof(float), stream);
  k_bn_stats   <<<dim3(B_, C_),                256, 0, stream>>>(x, ws);
  k_bn_finalize<<<1, 128,                           0, stream>>>(gamma, beta, ws);
  k_wrot       <<<dim3(NCH_, R_),              256, 0, stream>>>(cw, ws);
  k_sstats     <<<dim3(R_, C_, B_),            256, 0, stream>>>(x, ws, out);
  k_upool      <<<dim3((HW_+255)/256, R_, B_), 256, 0, stream>>>(x, ws);
  k_chatt      <<<B_, 256,                          0, stream>>>(fc1, fc2, ws);
  k_spatt      <<<dim3((HW_+255)/256, R_, B_), 256, 0, stream>>>(saw, ws);
  k_conv       <<<dim3(16, R_, B_),            512, 0, stream>>>(x, ws, out);
}

// Round 4
// 530.522 us; speedup vs baseline: 3.7818x; 1.1282x over previous
//
#include <hip/hip_runtime.h>
#include <hip/hip_bf16.h>
#include <math.h>

constexpr int B_ = 16, C_ = 96, O_ = 48, R_ = 4, H_ = 66, W_ = 66;
constexpr int HW_ = H_ * W_;            // 4356
constexpr int HO_ = 64, WO_ = 64;       // valid-conv output spatial
constexpr int OC_ = O_ + C_;            // 144 output channels
constexpr float EPS_ = 2e-5f;
constexpr int KP_ = 32;                 // planes per K-chunk
constexpr int NCH_ = (C_*R_)/KP_;       // 12 chunks
constexpr int ROWS_ = 16;               // out-rows per block
constexpr int SR_ = ROWS_ + 2;          // staged input rows (halo)
constexpr int GPC_ = SR_*W_;            // 1188 positions per quad-plane-group
constexpr int WIMG_ = 9*3*64*8;         // 13824 bf16 per (h,chunk) weight image

// workspace layout (float offsets)
constexpr int WS_SUM   = 0;
constexpr int WS_SUMSQ = WS_SUM + C_;
constexpr int WS_SCALE = WS_SUMSQ + C_;
constexpr int WS_SHIFT = WS_SCALE + C_;
constexpr int WS_SAVG  = WS_SHIFT + C_;                    // [B][C][R]
constexpr int WS_SMAX  = WS_SAVG + B_*C_*R_;
constexpr int WS_CHATT = WS_SMAX + B_*C_*R_;               // [B][h][C][r]
constexpr int WS_UMEAN = WS_CHATT + B_*R_*C_*R_;           // [B][r][HW]
constexpr int WS_UMAX  = WS_UMEAN + B_*R_*HW_;
constexpr int WS_SPATT = WS_UMAX + B_*R_*HW_;              // [B][h][HW]
constexpr int WS_WROT  = WS_SPATT + B_*R_*HW_;             // bf16 [h][chunk][tap][nt][lane][8]
// wrot shorts = 4*12*13824 = 663552 -> 331776 floats; total ws ~ 4.9 MB

typedef __attribute__((ext_vector_type(8))) __bf16 bf16x8;
typedef __attribute__((ext_vector_type(4))) float f32x4;

__device__ __forceinline__ float sigm(float v){ return 1.0f/(1.0f + __expf(-v)); }

// ---- K1: BN batch statistics ----
__global__ void k_bn_stats(const float* __restrict__ x, float* __restrict__ ws) {
  int b = blockIdx.x, c = blockIdx.y;
  const float4* p = (const float4*)(x + (size_t)(b*C_ + c) * (R_*HW_));
  int tid = threadIdx.x;
  float s = 0.f, ss = 0.f;
  for (int i = tid; i < R_*HW_/4; i += 256) {
    float4 v = p[i];
    s += v.x + v.y + v.z + v.w;
    ss += v.x*v.x + v.y*v.y + v.z*v.z + v.w*v.w;
  }
  __shared__ float rs[256], rq[256];
  rs[tid] = s; rq[tid] = ss; __syncthreads();
  for (int off = 128; off > 0; off >>= 1) {
    if (tid < off) { rs[tid] += rs[tid+off]; rq[tid] += rq[tid+off]; }
    __syncthreads();
  }
  if (tid == 0) {
    atomicAdd(&ws[WS_SUM + c], rs[0]);
    atomicAdd(&ws[WS_SUMSQ + c], rq[0]);
  }
}

// ---- K2: finalize scale/shift ----
__global__ void k_bn_finalize(const float* __restrict__ gamma, const float* __restrict__ beta,
                              float* __restrict__ ws) {
  int c = threadIdx.x;
  if (c < C_) {
    float n = (float)(B_ * R_ * HW_);
    float mu = ws[WS_SUM + c] / n;
    float var = ws[WS_SUMSQ + c] / n - mu*mu;
    float sc = gamma[c] * rsqrtf(var + EPS_);
    ws[WS_SCALE + c] = sc;
    ws[WS_SHIFT + c] = beta[c] - mu * sc;
  }
}

// ---- K3: per-(b,c,r) spatial mean/max of y + fused crop-copy to out ----
__global__ void k_sstats(const float* __restrict__ x, float* __restrict__ ws,
                         float* __restrict__ out) {
  int r = blockIdx.x, c = blockIdx.y, b = blockIdx.z;
  int tid = threadIdx.x;
  float sc = ws[WS_SCALE + c], sh = ws[WS_SHIFT + c];
  const float* xp = x + (size_t)((b*C_ + c)*R_ + r) * HW_;
  const float4* p = (const float4*)xp;
  float s = 0.f, m = 0.f;
  for (int i = tid; i < HW_/4; i += 256) {
    float4 v = p[i];
    float a0 = fmaxf(fmaf(v.x, sc, sh), 0.f);
    float a1 = fmaxf(fmaf(v.y, sc, sh), 0.f);
    float a2 = fmaxf(fmaf(v.z, sc, sh), 0.f);
    float a3 = fmaxf(fmaf(v.w, sc, sh), 0.f);
    s += a0+a1+a2+a3; m = fmaxf(fmaxf(fmaxf(m, a0), fmaxf(a1, a2)), a3);
  }
  float* op = out + ((size_t)(b*OC_ + O_ + c)*R_ + r)*((size_t)HO_*WO_);
  for (int e = tid; e < HO_*WO_/4; e += 256) {
    int row = e >> 4, c4 = e & 15;
    const float* sp2 = xp + (row+1)*W_ + c4*4 + 1;
    float4 v = make_float4(sp2[0], sp2[1], sp2[2], sp2[3]);
    *(float4*)(op + row*WO_ + c4*4) = v;
  }
  __shared__ float rs[256], rm[256];
  rs[tid] = s; rm[tid] = m; __syncthreads();
  for (int off = 128; off > 0; off >>= 1) {
    if (tid < off) { rs[tid] += rs[tid+off]; rm[tid] = fmaxf(rm[tid], rm[tid+off]); }
    __syncthreads();
  }
  if (tid == 0) {
    int idx = (b*C_ + c)*R_ + r;
    ws[WS_SAVG + idx] = rs[0] / (float)HW_;
    ws[WS_SMAX + idx] = rm[0];
  }
}

// ---- K4: channel-pooled maps u_mean/u_max ----
__global__ void k_upool(const float* __restrict__ x, float* __restrict__ ws) {
  int r = blockIdx.y, b = blockIdx.z;
  int pos = blockIdx.x*256 + threadIdx.x;
  if (pos >= HW_) return;
  float s = 0.f, m = 0.f;
  for (int c = 0; c < C_; ++c) {
    float v = fmaxf(fmaf(x[(size_t)((b*C_ + c)*R_ + r)*HW_ + pos],
                         ws[WS_SCALE+c], ws[WS_SHIFT+c]), 0.f);
    s += v; m = fmaxf(m, v);
  }
  int idx = (b*R_ + r)*HW_ + pos;
  ws[WS_UMEAN + idx] = s / (float)C_;
  ws[WS_UMAX + idx] = m;
}

// ---- K5: channel attention MLP ----
__global__ void k_chatt(const float* __restrict__ fc1, const float* __restrict__ fc2,
                        float* __restrict__ ws) {
  int b = blockIdx.x, tid = threadIdx.x;
  __shared__ float sA[C_*R_], sM[C_*R_], hs[8];
  for (int i = tid; i < C_*R_; i += 256) {
    sA[i] = ws[WS_SAVG + b*C_*R_ + i];
    sM[i] = ws[WS_SMAX + b*C_*R_ + i];
  }
  __syncthreads();
  if (tid < 8) {
    int h = tid >> 1, e = tid & 1;
    float aA = 0.f, aM = 0.f;
    for (int c = 0; c < C_; ++c)
      for (int r = 0; r < R_; ++r) {
        float w = fc1[(e*C_ + c)*R_ + ((r - h) & 3)];
        aA += sA[c*R_ + r] * w;
        aM += sM[c*R_ + r] * w;
      }
    hs[tid] = fmaxf(aA, 0.f) + fmaxf(aM, 0.f);
  }
  __syncthreads();
  for (int idx = tid; idx < R_*C_*R_; idx += 256) {
    int h = idx / (C_*R_);
    int c = (idx % (C_*R_)) / R_;
    int r = idx & 3;
    int rr = (r - h) & 3;
    float v = hs[h*2+0] * fc2[(c*2+0)*R_ + rr]
            + hs[h*2+1] * fc2[(c*2+1)*R_ + rr];
    ws[WS_CHATT + b*R_*C_*R_ + idx] = sigm(v);
  }
}

// ---- K6: spatial attention 7x7 group conv ----
__global__ void k_spatt(const float* __restrict__ saw, float* __restrict__ ws) {
  int h = blockIdx.y, b = blockIdx.z;
  int tid = threadIdx.x;
  __shared__ float wl[2*R_*49];
  for (int e = tid; e < 2*R_*49; e += 256) {
    int g = e / (R_*49);
    int s = (e / 49) % R_;
    int ij = e % 49;
    int i = ij / 7, j = ij % 7;
    int si, sj;
    if (h == 0)      { si = i;     sj = j;     }
    else if (h == 1) { si = j;     sj = 6 - i; }
    else if (h == 2) { si = 6 - i; sj = 6 - j; }
    else             { si = 6 - j; sj = i;     }
    int srot = (s - h) & 3;
    wl[e] = saw[(g*R_ + srot)*49 + si*7 + sj];
  }
  __syncthreads();
  int pos = blockIdx.x*256 + tid;
  if (pos >= HW_) return;
  int y = pos / W_, xx = pos % W_;
  float acc = 0.f;
  for (int g = 0; g < 2; ++g) {
    const float* u = ws + (g ? WS_UMAX : WS_UMEAN) + (size_t)b*R_*HW_;
    for (int s = 0; s < R_; ++s) {
      const float* up = u + s*HW_;
      const float* wp = wl + (g*R_ + s)*49;
      for (int i = 0; i < 7; ++i) {
        int yy = y + i - 3;
        if (yy < 0 || yy >= H_) continue;
        for (int j = 0; j < 7; ++j) {
          int xc = xx + j - 3;
          if (xc < 0 || xc >= W_) continue;
          acc += up[yy*W_ + xc] * wp[i*7 + j];
        }
      }
    }
  }
  ws[WS_SPATT + (b*R_ + h)*HW_ + pos] = sigm(acc);
}

// ---- K7: pre-rotate conv weights into lane-ordered MFMA fragment images ----
// wglob[h][chunk][tap][nt][lane][kk]: A-frag value = w[o=nt*16+(lane&15)]
//   [plane=chunk*32+(lane>>4)*8+kk] rotated by h. Conflict-free lane*16 reads.
__global__ void k_wrot(const float* __restrict__ cw, float* __restrict__ ws) {
  int chunk = blockIdx.x, h = blockIdx.y;
  __bf16* wp = (__bf16*)(ws + WS_WROT) + (size_t)(h*NCH_ + chunk)*WIMG_;
  for (int e = threadIdx.x; e < WIMG_; e += 256) {
    int kk = e & 7;
    int lane = (e >> 3) & 63;
    int nt = (e >> 9) % 3;
    int tap = e / (3*512);
    int o = nt*16 + (lane & 15);
    int plane = chunk*KP_ + (lane >> 4)*8 + kk;
    int c = plane >> 2, r = plane & 3;
    int rr = (r - h) & 3;
    int i = tap / 3, j = tap % 3;
    int si, sj;
    if (h == 0)      { si = i;     sj = j;     }
    else if (h == 1) { si = j;     sj = 2 - i; }
    else if (h == 2) { si = 2 - i; sj = 2 - j; }
    else             { si = 2 - j; sj = i;     }
    wp[e] = (__bf16)cw[((size_t)(o*C_ + c)*R_ + rr)*9 + si*3 + sj];
  }
}

// ---- K8: main conv via MFMA implicit GEMM ----
// Block 512 (8 waves) = 4 rowgroups x 2 colgroups. Out tile 16 rows x 64 cols
// x 48 O for one (b,h). Wave: 4 dy x 2 gi x 3 nt = 24 16x16 acc tiles.
// z LDS: quad-outer [q][pos][8planes] (uniform banks); w LDS: lane-ordered.
__global__ __launch_bounds__(512, 2) void k_conv(
    const float* __restrict__ x, const float* __restrict__ ws,
    float* __restrict__ out) {
  int ytile = blockIdx.x, h = blockIdx.y, b = blockIdx.z;
  int y0 = ytile * ROWS_;
  int tid = threadIdx.x;
  int lane = tid & 63, wave = tid >> 6;
  int m = lane & 15, quad = lane >> 4;
  int colgrp = wave & 1, rowgrp = wave >> 1;
  int dy0 = rowgrp * 4, colbase = colgrp * 32;

  __shared__ __align__(16) __bf16 zl[4*GPC_*8];   // 76032 B
  __shared__ __align__(16) __bf16 wl[WIMG_];      // 27648 B
  __shared__ float satt_l[GPC_];                  // 4752 B
  __shared__ float catt_l[C_*R_];
  __shared__ float scl[C_], shl[C_];

  const float* sp = ws + WS_SPATT + (size_t)(b*R_ + h)*HW_;
  for (int e = tid; e < GPC_; e += 512) satt_l[e] = sp[(y0 + e/W_)*W_ + e%W_];
  const float* chatt = ws + WS_CHATT + (size_t)(b*R_ + h)*C_*R_;
  for (int e = tid; e < C_*R_; e += 512) catt_l[e] = chatt[e];
  for (int e = tid; e < C_; e += 512) { scl[e] = ws[WS_SCALE+e]; shl[e] = ws[WS_SHIFT+e]; }

  f32x4 acc[4][2][3];
  #pragma unroll
  for (int dy = 0; dy < 4; ++dy)
    #pragma unroll
    for (int gi = 0; gi < 2; ++gi)
      #pragma unroll
      for (int nt = 0; nt < 3; ++nt) acc[dy][gi][nt] = (f32x4){0.f,0.f,0.f,0.f};

  const __bf16* wglob = (const __bf16*)(ws + WS_WROT) + (size_t)h*NCH_*WIMG_;
  int sq = tid & 3, sg0 = tid >> 2;          // staging: fixed quad per thread
  __syncthreads();                           // satt/catt/scl ready

  for (int chunk = 0; chunk < NCH_; ++chunk) {
    int pbase = chunk*KP_ + sq*8;            // first of this thread's 8 planes
    int cb = pbase >> 2;                     // 2 consecutive channels
    float sc0 = scl[cb], sh0 = shl[cb], sc1 = scl[cb+1], sh1 = shl[cb+1];
    float ca[8];
    #pragma unroll
    for (int kk = 0; kk < 8; ++kk) ca[kk] = catt_l[pbase + kk];

    // stage z: thread packs 8 planes of one (quad,pos) per ds_write_b128
    for (int g = sg0; g < GPC_; g += 128) {
      int row = g / W_, col = g - row*W_;
      const float* xp = x + (size_t)(b*C_*R_ + pbase)*HW_ + (y0+row)*W_ + col;
      float sa = satt_l[g];
      bf16x8 pk;
      #pragma unroll
      for (int kk = 0; kk < 8; ++kk) {
        float yv = fmaxf(fmaf(xp[kk*HW_], (kk < 4 ? sc0 : sc1),
                              (kk < 4 ? sh0 : sh1)), 0.f);
        pk[kk] = (__bf16)(yv * ca[kk] * sa);
      }
      *(bf16x8*)&zl[(sq*GPC_ + g)*8] = pk;
    }
    // stage weights: straight copy of lane-ordered image
    {
      const uint4* wsrc = (const uint4*)(wglob + (size_t)chunk*WIMG_);
      uint4* wdst = (uint4*)wl;
      for (int e = tid; e < WIMG_/8; e += 512) wdst[e] = wsrc[e];
    }
    __syncthreads();
    #pragma unroll
    for (int j = 0; j < 3; ++j) {
      bf16x8 zf[6][2];
      #pragma unroll
      for (int rr = 0; rr < 6; ++rr)
        #pragma unroll
        for (int gi = 0; gi < 2; ++gi)
          zf[rr][gi] = *(const bf16x8*)
              &zl[(quad*GPC_ + (dy0+rr)*W_ + colbase + gi*16 + m + j)*8];
      #pragma unroll
      for (int i = 0; i < 3; ++i) {
        int tap = i*3 + j;
        bf16x8 wf[3];
        #pragma unroll
        for (int nt = 0; nt < 3; ++nt)
          wf[nt] = *(const bf16x8*)&wl[((tap*3 + nt)*64 + lane)*8];
        #pragma unroll
        for (int dy = 0; dy < 4; ++dy)
          #pragma unroll
          for (int gi = 0; gi < 2; ++gi)
            #pragma unroll
            for (int nt = 0; nt < 3; ++nt)
              acc[dy][gi][nt] = __builtin_amdgcn_mfma_f32_16x16x32_bf16(
                  wf[nt], zf[dy+i][gi], acc[dy][gi][nt], 0, 0, 0);
      }
    }
    __syncthreads();   // all reads done before next chunk's staging
  }
  // epilogue: D layout col(n=spatial)=lane&15, row(m=o_local)=quad*4+e
  #pragma unroll
  for (int dy = 0; dy < 4; ++dy)
    #pragma unroll
    for (int gi = 0; gi < 2; ++gi)
      #pragma unroll
      for (int nt = 0; nt < 3; ++nt) {
        int col = colbase + gi*16 + m;
        #pragma unroll
        for (int e = 0; e < 4; ++e) {
          int o = nt*16 + quad*4 + e;
          out[((size_t)(b*OC_ + o)*R_ + h)*((size_t)HO_*WO_)
              + (y0 + dy0 + dy)*WO_ + col] = acc[dy][gi][nt][e];
        }
      }
}

extern "C" void kernel_launch(void* const* d_in, const int* in_sizes, int n_in,
                              void* d_out, int out_size, void* d_ws, size_t ws_size,
                              hipStream_t stream) {
  const float* x     = (const float*)d_in[0];
  const float* gamma = (const float*)d_in[1];
  const float* beta  = (const float*)d_in[2];
  const float* fc1   = (const float*)d_in[3];
  const float* fc2   = (const float*)d_in[4];
  const float* saw   = (const float*)d_in[5];
  const float* cw    = (const float*)d_in[6];
  float* out = (float*)d_out;
  float* ws = (float*)d_ws;

  hipMemsetAsync(d_ws, 0, WS_SCALE * sizeof(float), stream);
  k_bn_stats   <<<dim3(B_, C_),                256, 0, stream>>>(x, ws);
  k_bn_finalize<<<1, 128,                           0, stream>>>(gamma, beta, ws);
  k_wrot       <<<dim3(NCH_, R_),              256, 0, stream>>>(cw, ws);
  k_sstats     <<<dim3(R_, C_, B_),            256, 0, stream>>>(x, ws, out);
  k_upool      <<<dim3((HW_+255)/256, R_, B_), 256, 0, stream>>>(x, ws);
  k_chatt      <<<B_, 256,                          0, stream>>>(fc1, fc2, ws);
  k_spatt      <<<dim3((HW_+255)/256, R_, B_), 256, 0, stream>>>(saw, ws);
  k_conv       <<<dim3(HO_/ROWS_, R_, B_),     512, 0, stream>>>(x, ws, out);
}